// Round 2
// baseline (29474.725 us; speedup 1.0000x reference)
//
#include <hip/hip_runtime.h>

typedef float f32x4 __attribute__((ext_vector_type(4)));

#define BB 64
#define TT 1024
#define DIN 128
#define NB 256
#define KW 5
#define HID 512
#define LL 510
#define LT 32
#define NREC_BLK 256
#define NREC_THR 512
#define EPS 1e-5f

// ---------------- coherent (cross-XCD) memory helpers ----------------
// sc0 sc1 stores write through L2 to the coherence point (IF$); sc0 sc1 loads
// bypass L1/L2 and read the coherence point. No fences -> no L2 wb/inv.
__device__ __forceinline__ void st16_sys(float* p, f32x4 v) {
  asm volatile("global_store_dwordx4 %0, %1, off sc0 sc1" :: "v"(p), "v"(v) : "memory");
}
__device__ __forceinline__ void st4_sys(float* p, float v) {
  asm volatile("global_store_dword %0, %1, off sc0 sc1" :: "v"(p), "v"(v) : "memory");
}
__device__ __forceinline__ void ld16x4_sys(const float* a0, const float* a1,
                                           const float* a2, const float* a3,
                                           f32x4& r0, f32x4& r1, f32x4& r2, f32x4& r3) {
  asm volatile(
      "global_load_dwordx4 %0, %4, off sc0 sc1\n\t"
      "global_load_dwordx4 %1, %5, off sc0 sc1\n\t"
      "global_load_dwordx4 %2, %6, off sc0 sc1\n\t"
      "global_load_dwordx4 %3, %7, off sc0 sc1\n\t"
      "s_waitcnt vmcnt(0)"
      : "=&v"(r0), "=&v"(r1), "=&v"(r2), "=&v"(r3)
      : "v"(a0), "v"(a1), "v"(a2), "v"(a3)
      : "memory");
}
__device__ __forceinline__ void ld16x2_sys(const float* a0, const float* a1,
                                           f32x4& r0, f32x4& r1) {
  asm volatile(
      "global_load_dwordx4 %0, %2, off sc0 sc1\n\t"
      "global_load_dwordx4 %1, %3, off sc0 sc1\n\t"
      "s_waitcnt vmcnt(0)"
      : "=&v"(r0), "=&v"(r1)
      : "v"(a0), "v"(a1)
      : "memory");
}

// ---------------- Conv1d + ReLU + BatchNorm (eval) -> seq[L][B][NB] ----------------
__global__ __launch_bounds__(256) void conv_kernel(
    const float* __restrict__ x, const float* __restrict__ cw,
    const float* __restrict__ cb, const float* __restrict__ gma,
    const float* __restrict__ bta, const float* __restrict__ bmean,
    const float* __restrict__ bvar, float* __restrict__ seq)
{
  __shared__ float xt[2*LT+3][DIN];
  const int b = blockIdx.y, lc = blockIdx.x, tid = threadIdx.x;
  const int l0 = lc*LT, t0 = l0*2;

  const float4* x4 = (const float4*)(x + ((size_t)b*TT + t0)*DIN);
  for (int i = tid; i < (2*LT+3)*(DIN/4); i += 256) {
    const int r = i >> 5, c = i & 31;
    float4 v = make_float4(0.f, 0.f, 0.f, 0.f);
    if (t0 + r < TT) v = x4[(size_t)r*(DIN/4) + c];
    ((float4*)xt[r])[c] = v;
  }
  __syncthreads();

  const int f = tid;
  float acc[LT];
#pragma unroll
  for (int l = 0; l < LT; ++l) acc[l] = 0.f;

  const float* wr = cw + (size_t)f*(DIN*KW);
  for (int d = 0; d < DIN; ++d) {
    float xr[2*LT+3];
#pragma unroll
    for (int r = 0; r < 2*LT+3; ++r) xr[r] = xt[r][d];
#pragma unroll
    for (int k = 0; k < KW; ++k) {
      const float w = wr[d*KW + k];
#pragma unroll
      for (int l = 0; l < LT; ++l) acc[l] += w * xr[2*l + k];
    }
  }

  const float bias  = cb[f];
  const float scale = gma[f] * rsqrtf(bvar[f] + EPS);
  const float shift = bta[f] - bmean[f]*scale;
#pragma unroll
  for (int l = 0; l < LT; ++l) {
    const int ll = l0 + l;
    if (ll < LL) {
      float y = acc[l] + bias;
      y = fmaxf(y, 0.f);
      seq[((size_t)ll*BB + b)*NB + f] = y*scale + shift;
    }
  }
}

// ---------------- SkipLSTM recurrence ----------------
// 256 blocks: bg = blk>>6 (4 groups of 16 batches), js = blk&63 (8 hidden each).
// Weights register-resident. Cross-block h/dotp via sc0sc1 write-through stores +
// bypass loads; per-group monotonic atomic-counter barrier (no fences, no L2 flush).
__global__ __launch_bounds__(NREC_THR, 2) void rec_kernel(
    const float* __restrict__ seq, const float* __restrict__ wih,
    const float* __restrict__ whh, const float* __restrict__ bih,
    const float* __restrict__ bhh, const float* __restrict__ wu,
    const float* __restrict__ bu, float* __restrict__ hbuf,
    float* __restrict__ dotp, unsigned* __restrict__ cnts,
    float* __restrict__ out)
{
  __shared__ float h_lds[16][HID];    // 32 KB
  __shared__ float s_lds[16][NB];     // 16 KB
  __shared__ float part[8][16][32];   // 16 KB
  __shared__ float gact[16][32];      // 2 KB
  __shared__ float c_l[16][8];
  __shared__ float ut_l[16], u_l[16];

  const int tid = threadIdx.x;
  const int bg = blockIdx.x >> 6, js = blockIdx.x & 63;
  const int b0 = bg*16, j0 = js*8;
  const int q = tid >> 5, row = tid & 31;
  const int gi = row >> 3;
  const int jj = row & 7;
  const int grow = gi*HID + j0 + jj;
  const int wv = tid >> 6;

  // ---- permanent weight registers ----
  f32x4 wh[8], wi4[4];
  {
    const f32x4* whr = (const f32x4*)(whh + (size_t)grow*HID) + q*8;
#pragma unroll
    for (int i = 0; i < 8; ++i) wh[i] = whr[i];
    const f32x4* wir = (const f32x4*)(wih + (size_t)grow*NB) + q*4;
#pragma unroll
    for (int i = 0; i < 4; ++i) wi4[i] = wir[i];
  }
  const float bias = bih[grow] + bhh[grow];
  const float wur  = wu[j0 + (tid & 7)];
  const float buv  = bu[0];

  if (tid < 16) { ut_l[tid] = 1.f; u_l[tid] = 1.f; }
  if (tid < 128) c_l[tid>>3][tid&7] = 0.f;

  // initial seq[0] staging (plain cached loads; seq is read-only here)
  {
    const f32x4* sr = (const f32x4*)(seq + (size_t)0*BB*NB + (size_t)b0*NB);
    f32x4* sd = (f32x4*)s_lds;
    for (int i = tid; i < 16*NB/4; i += NREC_THR) sd[i] = sr[i];
  }
  __syncthreads();

  for (int t = 0; ; ++t) {
    // ---- phase B: partial dots (weights in regs, h/seq broadcast from LDS) ----
    {
      float accs[16];
      const f32x4* h4base = (const f32x4*)h_lds;
      const f32x4* s4base = (const f32x4*)s_lds;
      for (int b = 0; b < 16; ++b) {
        float a = 0.f;
        if (t > 0) {
          const f32x4* h4 = h4base + b*(HID/4) + q*8;
#pragma unroll
          for (int i = 0; i < 8; ++i) {
            const f32x4 hv = h4[i];
            a += wh[i].x*hv.x + wh[i].y*hv.y + wh[i].z*hv.z + wh[i].w*hv.w;
          }
        }
        const f32x4* s4 = s4base + b*(NB/4) + q*4;
#pragma unroll
        for (int i = 0; i < 4; ++i) {
          const f32x4 sv = s4[i];
          a += wi4[i].x*sv.x + wi4[i].y*sv.y + wi4[i].z*sv.z + wi4[i].w*sv.w;
        }
        accs[b] = a;
      }
#pragma unroll
      for (int b = 0; b < 16; ++b) {
        const float a = accs[b] + __shfl_xor(accs[b], 32);
        if ((tid & 32) == 0) part[wv][b][row] = a;
      }
    }
    __syncthreads();

    // ---- phase C1: reduce wave-partials, add bias, activate ----
    {
      const int cb2 = tid >> 5, crow = tid & 31;
      float v = bias;
#pragma unroll
      for (int p = 0; p < 8; ++p) v += part[p][cb2][crow];
      gact[cb2][crow] = ((crow >> 3) == 2) ? tanhf(v) : 1.f/(1.f + expf(-v));
    }
    __syncthreads();

    // ---- phase C2: state update; coherent stores of h and du-partials ----
    if (tid < 128) {
      const int b = tid >> 3, j = tid & 7;
      const float ig = gact[b][j],     fg = gact[b][8+j];
      const float gg = gact[b][16+j],  og = gact[b][24+j];
      const float cold = c_l[b][j], u = u_l[b];
      const float cnew = fg*cold + ig*gg;
      const float ct   = u*cnew + (1.f-u)*cold;
      const float hold = (t > 0) ? h_lds[b][j0+j] : 0.f;
      const float ht   = u*(og*tanhf(ct)) + (1.f-u)*hold;
      c_l[b][j] = ct;
      if (t == LL-1) {
        out[(size_t)(b0+b)*HID + j0 + j] = ht;
      } else {
        st4_sys(hbuf + (size_t)(t&1)*BB*HID + (size_t)(b0+b)*HID + j0 + j, ht);
        float p = ct * wur;
        p += __shfl_xor(p, 1, 8);
        p += __shfl_xor(p, 2, 8);
        p += __shfl_xor(p, 4, 8);
        if (j == 0) st4_sys(dotp + (size_t)(t&1)*BB*64 + (size_t)(b0+b)*64 + js, p);
      }
    }
    if (t == LL-1) break;

    // ---- barrier: drain coherent stores, then per-group monotonic counter ----
    asm volatile("s_waitcnt vmcnt(0)" ::: "memory");
    __syncthreads();
    if (tid == 0) {
      unsigned* c = cnts + bg*16;          // 64B-separated counters
      __hip_atomic_fetch_add(c, 1u, __ATOMIC_RELAXED, __HIP_MEMORY_SCOPE_AGENT);
      const unsigned tgt = 64u*(unsigned)(t+1);
      while (__hip_atomic_load(c, __ATOMIC_RELAXED, __HIP_MEMORY_SCOPE_AGENT) < tgt)
        __builtin_amdgcn_s_sleep(2);
    }
    __syncthreads();

    // ---- phase A (for step t+1): stage h(t), seq[t+1]; update ut/u from dotp(t) ----
    {
      const float* hb = hbuf + (size_t)(t&1)*BB*HID + (size_t)b0*HID;
      f32x4 r0, r1, r2, r3;
      ld16x4_sys(hb + 4*(size_t)tid,
                 hb + 4*((size_t)tid + 512),
                 hb + 4*((size_t)tid + 1024),
                 hb + 4*((size_t)tid + 1536),
                 r0, r1, r2, r3);
      f32x4* hd = (f32x4*)h_lds;
      hd[tid] = r0; hd[tid+512] = r1; hd[tid+1024] = r2; hd[tid+1536] = r3;
    }
    if (tid < 128) {
      const int b = tid >> 3, k = tid & 7;
      const float* dp = dotp + (size_t)(t&1)*BB*64 + (size_t)(b0+b)*64 + k*8;
      f32x4 r0, r1;
      ld16x2_sys(dp, dp + 4, r0, r1);
      float s = r0.x+r0.y+r0.z+r0.w + r1.x+r1.y+r1.z+r1.w;
      s += __shfl_xor(s, 1, 8);
      s += __shfl_xor(s, 2, 8);
      s += __shfl_xor(s, 4, 8);
      if (k == 0) {
        const float du  = 1.f/(1.f + expf(-(s + buv)));
        const float utv = ut_l[b], up = u_l[b];
        const float utn = up*du + (1.f-up)*(utv + fminf(du, 1.f-utv));
        ut_l[b] = utn;
        u_l[b]  = rintf(utn);
      }
    }
    {
      const f32x4* sr = (const f32x4*)(seq + (size_t)(t+1)*BB*NB + (size_t)b0*NB);
      f32x4* sd = (f32x4*)s_lds;
      for (int i = tid; i < 16*NB/4; i += NREC_THR) sd[i] = sr[i];
    }
    __syncthreads();
  }
}

extern "C" void kernel_launch(void* const* d_in, const int* in_sizes, int n_in,
                              void* d_out, int out_size, void* d_ws, size_t ws_size,
                              hipStream_t stream) {
  const float* x    = (const float*)d_in[0];
  const float* cw   = (const float*)d_in[1];
  const float* cb   = (const float*)d_in[2];
  const float* gma  = (const float*)d_in[3];
  const float* bta  = (const float*)d_in[4];
  const float* bmean= (const float*)d_in[5];
  const float* bvar = (const float*)d_in[6];
  const float* wih  = (const float*)d_in[7];
  const float* whh  = (const float*)d_in[8];
  const float* bih  = (const float*)d_in[9];
  const float* bhh  = (const float*)d_in[10];
  const float* wu   = (const float*)d_in[11];
  const float* bu   = (const float*)d_in[12];
  float* out = (float*)d_out;

  float* ws   = (float*)d_ws;
  float* seq  = ws;                                  // L*B*NB  = 8,355,840 f
  float* hbuf = seq  + (size_t)LL*BB*NB;             // 2*B*HID = 65,536 f
  float* dotp = hbuf + (size_t)2*BB*HID;             // 2*B*64  = 8,192 f
  unsigned* cnts = (unsigned*)(dotp + (size_t)2*BB*64);  // 4 x 64B counters

  hipMemsetAsync(cnts, 0, 256, stream);

  hipLaunchKernelGGL(conv_kernel, dim3(16, 64), dim3(256), 0, stream,
                     x, cw, cb, gma, bta, bmean, bvar, seq);

  void* args[] = { (void*)&seq, (void*)&wih, (void*)&whh, (void*)&bih, (void*)&bhh,
                   (void*)&wu, (void*)&bu, (void*)&hbuf, (void*)&dotp,
                   (void*)&cnts, (void*)&out };
  hipLaunchCooperativeKernel(rec_kernel, dim3(NREC_BLK), dim3(NREC_THR),
                             args, 0, stream);
}

// Round 3
// 27968.402 us; speedup vs baseline: 1.0539x; 1.0539x over previous
//
#include <hip/hip_runtime.h>

typedef float f32x4 __attribute__((ext_vector_type(4)));

#define BB 64
#define TT 1024
#define DIN 128
#define NB 256
#define KW 5
#define HID 512
#define LL 510
#define LT 32
#define NREC_BLK 256
#define NREC_THR 512
#define EPS 1e-5f

// ---------------- coherent (cross-XCD) memory helpers ----------------
__device__ __forceinline__ void st4_sys(float* p, float v) {
  asm volatile("global_store_dword %0, %1, off sc0 sc1" :: "v"(p), "v"(v) : "memory");
}
__device__ __forceinline__ void st4_sys_u32(unsigned* p, unsigned v) {
  asm volatile("global_store_dword %0, %1, off sc0 sc1" :: "v"(p), "v"(v) : "memory");
}
__device__ __forceinline__ unsigned ld4_sys_u32(const unsigned* p) {
  unsigned v;
  asm volatile("global_load_dword %0, %1, off sc0 sc1\n\ts_waitcnt vmcnt(0)"
               : "=v"(v) : "v"(p) : "memory");
  return v;
}
__device__ __forceinline__ void ld16x4_sys(const float* a0, const float* a1,
                                           const float* a2, const float* a3,
                                           f32x4& r0, f32x4& r1, f32x4& r2, f32x4& r3) {
  asm volatile(
      "global_load_dwordx4 %0, %4, off sc0 sc1\n\t"
      "global_load_dwordx4 %1, %5, off sc0 sc1\n\t"
      "global_load_dwordx4 %2, %6, off sc0 sc1\n\t"
      "global_load_dwordx4 %3, %7, off sc0 sc1\n\t"
      "s_waitcnt vmcnt(0)"
      : "=&v"(r0), "=&v"(r1), "=&v"(r2), "=&v"(r3)
      : "v"(a0), "v"(a1), "v"(a2), "v"(a3)
      : "memory");
}
__device__ __forceinline__ void ld16x2_sys(const float* a0, const float* a1,
                                           f32x4& r0, f32x4& r1) {
  asm volatile(
      "global_load_dwordx4 %0, %2, off sc0 sc1\n\t"
      "global_load_dwordx4 %1, %3, off sc0 sc1\n\t"
      "s_waitcnt vmcnt(0)"
      : "=&v"(r0), "=&v"(r1)
      : "v"(a0), "v"(a1)
      : "memory");
}

// ---------------- Conv1d + ReLU + BatchNorm (eval) -> seq[L][B][NB] ----------------
__global__ __launch_bounds__(256) void conv_kernel(
    const float* __restrict__ x, const float* __restrict__ cw,
    const float* __restrict__ cb, const float* __restrict__ gma,
    const float* __restrict__ bta, const float* __restrict__ bmean,
    const float* __restrict__ bvar, float* __restrict__ seq)
{
  __shared__ float xt[2*LT+3][DIN];
  const int b = blockIdx.y, lc = blockIdx.x, tid = threadIdx.x;
  const int l0 = lc*LT, t0 = l0*2;

  const float4* x4 = (const float4*)(x + ((size_t)b*TT + t0)*DIN);
  for (int i = tid; i < (2*LT+3)*(DIN/4); i += 256) {
    const int r = i >> 5, c = i & 31;
    float4 v = make_float4(0.f, 0.f, 0.f, 0.f);
    if (t0 + r < TT) v = x4[(size_t)r*(DIN/4) + c];
    ((float4*)xt[r])[c] = v;
  }
  __syncthreads();

  const int f = tid;
  float acc[LT];
#pragma unroll
  for (int l = 0; l < LT; ++l) acc[l] = 0.f;

  const float* wr = cw + (size_t)f*(DIN*KW);
  for (int d = 0; d < DIN; ++d) {
    float xr[2*LT+3];
#pragma unroll
    for (int r = 0; r < 2*LT+3; ++r) xr[r] = xt[r][d];
#pragma unroll
    for (int k = 0; k < KW; ++k) {
      const float w = wr[d*KW + k];
#pragma unroll
      for (int l = 0; l < LT; ++l) acc[l] += w * xr[2*l + k];
    }
  }

  const float bias  = cb[f];
  const float scale = gma[f] * rsqrtf(bvar[f] + EPS);
  const float shift = bta[f] - bmean[f]*scale;
#pragma unroll
  for (int l = 0; l < LT; ++l) {
    const int ll = l0 + l;
    if (ll < LL) {
      float y = acc[l] + bias;
      y = fmaxf(y, 0.f);
      seq[((size_t)ll*BB + b)*NB + f] = y*scale + shift;
    }
  }
}

// ---------------- SkipLSTM recurrence ----------------
// 256 blocks: bg = blk>>6 (4 groups of 16 batches), js = blk&63 (8 hidden each).
// Weights register-resident. CACHED: h/dotp in depth-LL rings, written sc0sc1
// (write-through -> MALL), read with PLAIN cached loads (fresh address per step,
// L2 can never be stale; 8 blocks/XCD share one L2 fetch). Barrier: one relaxed
// agent atomicAdd per block (arrival) + last-arriver releases a flag; others
// poll the flag with READ-ONLY sc0sc1 loads.
template<bool CACHED>
__global__ __launch_bounds__(NREC_THR, 2) void rec_kernel(
    const float* __restrict__ seq, const float* __restrict__ wih,
    const float* __restrict__ whh, const float* __restrict__ bih,
    const float* __restrict__ bhh, const float* __restrict__ wu,
    const float* __restrict__ bu, float* __restrict__ hbuf,
    float* __restrict__ dotp, unsigned* __restrict__ cnts,
    unsigned* __restrict__ flags, float* __restrict__ out)
{
  __shared__ float h_lds[16][HID];    // 32 KB
  __shared__ float s_lds[16][NB];     // 16 KB
  __shared__ float part[8][16][32];   // 16 KB
  __shared__ float gact[16][32];      // 2 KB
  __shared__ float c_l[16][8];
  __shared__ float ut_l[16], u_l[16];

  const int tid = threadIdx.x;
  const int bg = blockIdx.x >> 6, js = blockIdx.x & 63;
  const int b0 = bg*16, j0 = js*8;
  const int q = tid >> 5, row = tid & 31;
  const int gi = row >> 3;
  const int jj = row & 7;
  const int grow = gi*HID + j0 + jj;
  const int wv = tid >> 6;

  // ---- permanent weight registers ----
  f32x4 wh[8], wi4[4];
  {
    const f32x4* whr = (const f32x4*)(whh + (size_t)grow*HID) + q*8;
#pragma unroll
    for (int i = 0; i < 8; ++i) wh[i] = whr[i];
    const f32x4* wir = (const f32x4*)(wih + (size_t)grow*NB) + q*4;
#pragma unroll
    for (int i = 0; i < 4; ++i) wi4[i] = wir[i];
  }
  const float bias = bih[grow] + bhh[grow];
  const float wur  = wu[j0 + (tid & 7)];
  const float buv  = bu[0];

  if (tid < 16) { ut_l[tid] = 1.f; u_l[tid] = 1.f; }
  if (tid < 128) c_l[tid>>3][tid&7] = 0.f;

  // initial seq[0] staging
  {
    const f32x4* sr = (const f32x4*)(seq + (size_t)b0*NB);
    f32x4* sd = (f32x4*)s_lds;
    for (int i = tid; i < 16*NB/4; i += NREC_THR) sd[i] = sr[i];
  }
  __syncthreads();

  for (int t = 0; ; ++t) {
    const size_t idx = CACHED ? (size_t)t : (size_t)(t & 1);

    // ---- phase B: partial dots (weights in regs, h/seq broadcast from LDS) ----
    {
      float accs[16];
      const f32x4* h4base = (const f32x4*)h_lds;
      const f32x4* s4base = (const f32x4*)s_lds;
      for (int b = 0; b < 16; ++b) {
        float a = 0.f;
        if (t > 0) {
          const f32x4* h4 = h4base + b*(HID/4) + q*8;
#pragma unroll
          for (int i = 0; i < 8; ++i) {
            const f32x4 hv = h4[i];
            a += wh[i].x*hv.x + wh[i].y*hv.y + wh[i].z*hv.z + wh[i].w*hv.w;
          }
        }
        const f32x4* s4 = s4base + b*(NB/4) + q*4;
#pragma unroll
        for (int i = 0; i < 4; ++i) {
          const f32x4 sv = s4[i];
          a += wi4[i].x*sv.x + wi4[i].y*sv.y + wi4[i].z*sv.z + wi4[i].w*sv.w;
        }
        accs[b] = a;
      }
#pragma unroll
      for (int b = 0; b < 16; ++b) {
        const float a = accs[b] + __shfl_xor(accs[b], 32);
        if ((tid & 32) == 0) part[wv][b][row] = a;
      }
    }
    __syncthreads();

    // ---- phase C1: reduce wave-partials, add bias, activate ----
    {
      const int cb2 = tid >> 5, crow = tid & 31;
      float v = bias;
#pragma unroll
      for (int p = 0; p < 8; ++p) v += part[p][cb2][crow];
      gact[cb2][crow] = ((crow >> 3) == 2) ? tanhf(v) : 1.f/(1.f + expf(-v));
    }
    __syncthreads();

    // ---- phase C2: state update; write-through stores of h and du-partials ----
    if (tid < 128) {
      const int b = tid >> 3, j = tid & 7;
      const float ig = gact[b][j],     fg = gact[b][8+j];
      const float gg = gact[b][16+j],  og = gact[b][24+j];
      const float cold = c_l[b][j], u = u_l[b];
      const float cnew = fg*cold + ig*gg;
      const float ct   = u*cnew + (1.f-u)*cold;
      const float hold = (t > 0) ? h_lds[b][j0+j] : 0.f;
      const float ht   = u*(og*tanhf(ct)) + (1.f-u)*hold;
      c_l[b][j] = ct;
      if (t == LL-1) {
        out[(size_t)(b0+b)*HID + j0 + j] = ht;
      } else {
        st4_sys(hbuf + idx*BB*HID + (size_t)(b0+b)*HID + j0 + j, ht);
        float p = ct * wur;
        p += __shfl_xor(p, 1, 8);
        p += __shfl_xor(p, 2, 8);
        p += __shfl_xor(p, 4, 8);
        if (j == 0) st4_sys(dotp + idx*BB*64 + (size_t)(b0+b)*64 + js, p);
      }
    }
    if (t == LL-1) break;

    // ---- barrier: drain stores; arrival add; last-arriver releases flag ----
    asm volatile("s_waitcnt vmcnt(0)" ::: "memory");
    __syncthreads();
    if (tid == 0) {
      const unsigned tgt = 64u*(unsigned)(t+1);
      unsigned* cp = cnts + bg*16;
      unsigned* fp = flags + bg*16;
      const unsigned old = __hip_atomic_fetch_add(cp, 1u, __ATOMIC_RELAXED,
                                                  __HIP_MEMORY_SCOPE_AGENT);
      if (old == tgt - 1u) {
        st4_sys_u32(fp, tgt);            // release: all 64 blocks arrived
      } else {
        unsigned f = ld4_sys_u32(fp);
        while (f < tgt) { __builtin_amdgcn_s_sleep(4); f = ld4_sys_u32(fp); }
      }
    }
    __syncthreads();

    // ---- phase A (for step t+1): stage h(t), seq[t+1]; update ut/u ----
    {
      const float* hb = hbuf + idx*BB*HID + (size_t)b0*HID;
      f32x4* hd = (f32x4*)h_lds;
      if constexpr (CACHED) {
        const f32x4* hr = (const f32x4*)hb;
#pragma unroll
        for (int i = 0; i < 4; ++i) hd[tid + 512*i] = hr[tid + 512*i];
      } else {
        f32x4 r0, r1, r2, r3;
        ld16x4_sys(hb + 4*(size_t)tid, hb + 4*((size_t)tid + 512),
                   hb + 4*((size_t)tid + 1024), hb + 4*((size_t)tid + 1536),
                   r0, r1, r2, r3);
        hd[tid] = r0; hd[tid+512] = r1; hd[tid+1024] = r2; hd[tid+1536] = r3;
      }
    }
    if (tid < 128) {
      const int b = tid >> 3, k = tid & 7;
      const float* dp = dotp + idx*BB*64 + (size_t)(b0+b)*64 + k*8;
      f32x4 r0, r1;
      if constexpr (CACHED) {
        r0 = ((const f32x4*)dp)[0]; r1 = ((const f32x4*)dp)[1];
      } else {
        ld16x2_sys(dp, dp + 4, r0, r1);
      }
      float s = r0.x+r0.y+r0.z+r0.w + r1.x+r1.y+r1.z+r1.w;
      s += __shfl_xor(s, 1, 8);
      s += __shfl_xor(s, 2, 8);
      s += __shfl_xor(s, 4, 8);
      if (k == 0) {
        const float du  = 1.f/(1.f + expf(-(s + buv)));
        const float utv = ut_l[b], up = u_l[b];
        const float utn = up*du + (1.f-up)*(utv + fminf(du, 1.f-utv));
        ut_l[b] = utn;
        u_l[b]  = rintf(utn);
      }
    }
    {
      const f32x4* sr = (const f32x4*)(seq + (size_t)(t+1)*BB*NB + (size_t)b0*NB);
      f32x4* sd = (f32x4*)s_lds;
      for (int i = tid; i < 16*NB/4; i += NREC_THR) sd[i] = sr[i];
    }
    __syncthreads();
  }
}

extern "C" void kernel_launch(void* const* d_in, const int* in_sizes, int n_in,
                              void* d_out, int out_size, void* d_ws, size_t ws_size,
                              hipStream_t stream) {
  const float* x    = (const float*)d_in[0];
  const float* cw   = (const float*)d_in[1];
  const float* cb   = (const float*)d_in[2];
  const float* gma  = (const float*)d_in[3];
  const float* bta  = (const float*)d_in[4];
  const float* bmean= (const float*)d_in[5];
  const float* bvar = (const float*)d_in[6];
  const float* wih  = (const float*)d_in[7];
  const float* whh  = (const float*)d_in[8];
  const float* bih  = (const float*)d_in[9];
  const float* bhh  = (const float*)d_in[10];
  const float* wu   = (const float*)d_in[11];
  const float* bu   = (const float*)d_in[12];
  float* out = (float*)d_out;

  float* ws = (float*)d_ws;
  const size_t SEQ_F = (size_t)LL*BB*NB;           // 8,355,840 f
  float*    seq   = ws;
  unsigned* cnts  = (unsigned*)(seq + SEQ_F);      // 64 u32
  unsigned* flags = cnts + 64;                     // 64 u32
  float*    dotp  = (float*)(flags + 64);

  // cached-ring footprint: seq + 128 u32 + LL*B*64 (dotp) + LL*B*512 (hbuf)
  const size_t need_cached =
      (SEQ_F + 128 + (size_t)LL*BB*64 + (size_t)LL*BB*HID) * 4;
  const bool cached = ws_size >= need_cached;

  float* hbuf = dotp + (cached ? (size_t)LL*BB*64 : (size_t)2*BB*64);

  hipMemsetAsync(cnts, 0, 512, stream);

  hipLaunchKernelGGL(conv_kernel, dim3(16, 64), dim3(256), 0, stream,
                     x, cw, cb, gma, bta, bmean, bvar, seq);

  void* args[] = { (void*)&seq, (void*)&wih, (void*)&whh, (void*)&bih, (void*)&bhh,
                   (void*)&wu, (void*)&bu, (void*)&hbuf, (void*)&dotp,
                   (void*)&cnts, (void*)&flags, (void*)&out };
  if (cached)
    hipLaunchCooperativeKernel(reinterpret_cast<void*>(rec_kernel<true>),
                               dim3(NREC_BLK), dim3(NREC_THR), args, 0, stream);
  else
    hipLaunchCooperativeKernel(reinterpret_cast<void*>(rec_kernel<false>),
                               dim3(NREC_BLK), dim3(NREC_THR), args, 0, stream);
}